// Round 9
// baseline (343.324 us; speedup 1.0000x reference)
//
#include <hip/hip_runtime.h>
#include <hip/hip_bf16.h>
#include <math.h>

// ---- problem constants ----
#define NN 32768
#define D 512
#define NL 8
#define BM 128          // GEMM M tile (level segments padded to this)
#define BN 128          // GEMM N tile
#define PADMAX 33792    // max padded rows: <=264 tiles of 128
#define MT_MAX 264

typedef __attribute__((ext_vector_type(8))) short short8;
typedef __attribute__((ext_vector_type(8))) __bf16 bf16x8;
typedef __attribute__((ext_vector_type(4))) float f32x4;
typedef __attribute__((ext_vector_type(4))) unsigned short us4;

// async global->LDS, 16B per lane; LDS dest is wave-uniform base + lane*16
#define GLDS16(gsrc, ldst) __builtin_amdgcn_global_load_lds( \
    (const __attribute__((address_space(1))) unsigned int*)(gsrc), \
    (__attribute__((address_space(3))) unsigned int*)(ldst), 16, 0, 0)

__device__ __forceinline__ unsigned short f2bf(float f){
  unsigned u = __builtin_bit_cast(unsigned, f);
  u += 0x7FFFu + ((u>>16)&1u);           // RNE
  return (unsigned short)(u>>16);
}
__device__ __forceinline__ float bf2f(unsigned short s){
  return __builtin_bit_cast(float, ((unsigned)s)<<16);
}
__device__ __forceinline__ float tanh_fast(float x){
  float e = __expf(2.f*x);               // v_exp-based; inf/0 saturate correctly
  return 1.f - 2.f*__builtin_amdgcn_rcpf(1.f+e);
}

// ---- ws bookkeeping kernels ----
__global__ void k_zero(float* w0){
  int t = blockIdx.x*blockDim.x + threadIdx.x;
  for(int i=t;i<4160;i+=gridDim.x*blockDim.x) w0[i]=0.f;  // counts/cursors/poff/sums
}

__global__ void k_hist(const int* __restrict__ lv, int* __restrict__ counts){
  __shared__ int h[NL];
  if(threadIdx.x<NL) h[threadIdx.x]=0;
  __syncthreads();
  for(int i=blockIdx.x*blockDim.x+threadIdx.x; i<NN; i+=gridDim.x*blockDim.x)
    atomicAdd(&h[lv[i]],1);
  __syncthreads();
  if(threadIdx.x<NL) atomicAdd(&counts[threadIdx.x], h[threadIdx.x]);
}

__global__ void k_offsets(const int* __restrict__ counts, int* __restrict__ poff, int* __restrict__ cursors){
  if(threadIdx.x==0 && blockIdx.x==0){
    int acc=0;
    for(int l=0;l<NL;l++){ poff[l]=acc; cursors[l]=acc; acc += (counts[l]+BM-1)/BM*BM; }
    poff[NL]=acc;
  }
}

// contention-free scatter: LDS rank + one global atomic per (block, level)
__global__ __launch_bounds__(256) void k_scatter(const int* __restrict__ lv, int* __restrict__ cursors, int* __restrict__ perm){
  __shared__ int h[NL];
  __shared__ int base[NL];
  int t = threadIdx.x;
  if(t<NL) h[t]=0;
  __syncthreads();
  int i = blockIdx.x*256 + t;
  int lvl = 0, rank = 0;
  if(i<NN){ lvl = lv[i]; rank = atomicAdd(&h[lvl],1); }
  __syncthreads();
  if(t<NL) base[t] = (h[t]>0) ? atomicAdd(&cursors[t], h[t]) : 0;
  __syncthreads();
  if(i<NN) perm[base[lvl] + rank] = i;
}

// ---- transpose+convert weights: Wt[n][k] bf16 (so MFMA B-frag reads are contiguous) ----
__global__ __launch_bounds__(256) void k_trans(const float* __restrict__ Wp, const float* __restrict__ W1a,
                                               unsigned short* __restrict__ WtP, unsigned short* __restrict__ Wt1a){
  int m = blockIdx.z;
  const float* src = (m<NL)? Wp + (size_t)m*D*D : W1a;
  unsigned short* dst = (m<NL)? WtP + (size_t)m*D*D : Wt1a;
  __shared__ unsigned short t[64][68];
  int k0=blockIdx.x*64, n0=blockIdx.y*64;
  int c = threadIdx.x&63, r4 = threadIdx.x>>6;
  for(int p=0;p<64;p+=4){ int r=p+r4; t[r][c] = f2bf(src[(size_t)(k0+r)*D + n0+c]); }
  __syncthreads();
  for(int p=0;p<64;p+=4){ int r=p+r4; dst[(size_t)(n0+r)*D + k0+c] = t[c][r]; }
}

// ---- gather node rows into level-sorted padded order, fp32 -> bf16 (grid-stride) ----
__global__ __launch_bounds__(256) void k_gather(const float* __restrict__ X, const int* __restrict__ perm,
                                                const int* __restrict__ poff, const int* __restrict__ counts,
                                                unsigned short* __restrict__ Xg){
  __shared__ int sPo[NL+1];
  __shared__ int sCt[NL];
  if(threadIdx.x < NL+1) sPo[threadIdx.x] = poff[threadIdx.x];
  if(threadIdx.x < NL)   sCt[threadIdx.x] = counts[threadIdx.x];
  int pf[NL+1];
  #pragma unroll
  for(int i=0;i<=NL;i++) pf[i]=poff[i];
  __syncthreads();
  int t = threadIdx.x & 127;
  int half = threadIdx.x >> 7;
  for(int r = blockIdx.x*2 + half; r < pf[NL]; r += gridDim.x*2){
    int lvl=0;
    #pragma unroll
    for(int i=1;i<NL;i++) lvl += (r>=pf[i]);
    int idx = -1;
    if(r - sPo[lvl] < sCt[lvl]) idx = perm[r];
    us4 pv = (us4){0,0,0,0};
    if(idx>=0){
      f32x4 x = *(const f32x4*)(X + (size_t)idx*D + t*4);
      #pragma unroll
      for(int e=0;e<4;e++) pv[e] = f2bf(x[e]);
    }
    *(us4*)(Xg + (size_t)r*D + t*4) = pv;
  }
}

// ---- GEMM1 (projection): Hg[row][n] = Xg[row][:] @ WtP_lvl[n][:] + bias; level sums ----
__global__ __launch_bounds__(256) void k_gemm(
    const unsigned short* __restrict__ Xs,
    const unsigned short* __restrict__ Wt,
    const float* __restrict__ bias,
    unsigned short* __restrict__ Out,
    float* __restrict__ sums,
    const int* __restrict__ poff,
    const int* __restrict__ counts)
{
  __shared__ __attribute__((aligned(16))) unsigned short Asb[BM*64];  // 16KB, linear [row][k]
  __shared__ __attribute__((aligned(16))) unsigned short Bsb[BN*64];  // 16KB, linear [n][k]
  __shared__ float lsum[BN];
  int row0 = blockIdx.x*BM;
  if(row0 >= poff[NL]) return;
  int n0 = blockIdx.y*BN;
  int lvl = 0;
  while(row0 >= poff[lvl+1]) lvl++;
  const unsigned short* Wb = Wt + (size_t)lvl*D*D;
  int tid = threadIdx.x;
  if(tid<BN) lsum[tid]=0.f;
  int l = tid&63, w = tid>>6;
  int wm = w>>1, wn = w&1;           // 2x2 waves -> 64x64 per wave
  int l15 = l&15, lhi = l>>4;
  int lo = (l>>3)*D + (l&7)*8;       // per-lane source offset: 8 rows x 8 granules
  const unsigned short* Abase = Xs + (size_t)row0*D + lo;
  const unsigned short* Bbase = Wb + (size_t)n0*D + lo;
  f32x4 acc[4][4];
  #pragma unroll
  for(int i=0;i<4;i++)
    #pragma unroll
    for(int j=0;j<4;j++) acc[i][j] = (f32x4){0.f,0.f,0.f,0.f};

  for(int kt=0;kt<D/64;kt++){
    int k0 = kt*64;
    #pragma unroll
    for(int i=0;i<4;i++)
      GLDS16(Abase + (size_t)((w*4+i)*8)*D + k0, Asb + (w*4+i)*512);
    #pragma unroll
    for(int i=0;i<4;i++)
      GLDS16(Bbase + (size_t)((w*4+i)*8)*D + k0, Bsb + (w*4+i)*512);
    __syncthreads();
    #pragma unroll
    for(int kk=0;kk<2;kk++){
      bf16x8 af[4], bg[4];
      #pragma unroll
      for(int fm=0;fm<4;fm++)
        af[fm] = __builtin_bit_cast(bf16x8, *(const short8*)(Asb + (wm*64+fm*16+l15)*64 + kk*32 + lhi*8));
      #pragma unroll
      for(int fn=0;fn<4;fn++)
        bg[fn] = __builtin_bit_cast(bf16x8, *(const short8*)(Bsb + (wn*64+fn*16+l15)*64 + kk*32 + lhi*8));
      #pragma unroll
      for(int fm=0;fm<4;fm++)
        #pragma unroll
        for(int fn=0;fn<4;fn++)
          acc[fm][fn] = __builtin_amdgcn_mfma_f32_16x16x32_bf16(af[fm], bg[fn], acc[fm][fn], 0,0,0);
    }
    __syncthreads();
  }
  // epilogue: bias, bf16 store, masked column sums (for level means)
  int cnt = counts[lvl], pb = poff[lvl];
  float csum[4] = {0.f,0.f,0.f,0.f};
  #pragma unroll
  for(int fn=0;fn<4;fn++){
    int col = n0 + wn*64 + fn*16 + l15;
    float bia = bias[lvl*D + col];
    #pragma unroll
    for(int fm=0;fm<4;fm++){
      #pragma unroll
      for(int j=0;j<4;j++){
        int grow = row0 + wm*64 + fm*16 + lhi*4 + j;   // verified C/D mapping
        float v = acc[fm][fn][j] + bia;
        Out[(size_t)grow*D + col] = f2bf(v);
        if((grow-pb)<cnt) csum[fn] += v;
      }
    }
  }
  #pragma unroll
  for(int fn=0;fn<4;fn++){
    float s = csum[fn];
    s += __shfl_xor(s,16);
    s += __shfl_xor(s,32);
    if(lhi==0) atomicAdd(&lsum[wn*64+fn*16+l15], s);
  }
  __syncthreads();
  if(tid<BN) atomicAdd(&sums[(size_t)lvl*D + n0 + tid], lsum[tid]);
}

// ---- means -> Bpre = means@W1b (b1 absorbed downstream) ; MW = means@Wout ----
__global__ __launch_bounds__(128) void k_small(
    const float* __restrict__ sums, const int* __restrict__ counts,
    const float* __restrict__ W1b,
    const float* __restrict__ Wout, float* __restrict__ Bpre, float* __restrict__ MW)
{
  int lvl = blockIdx.x, jc = blockIdx.y, t = threadIdx.x;
  __shared__ float mean[D];
  int c = counts[lvl];
  float inv = 1.f / (float)(c>0?c:1);
  for(int k=t;k<D;k+=128) mean[k] = sums[lvl*D+k]*inv;
  __syncthreads();
  int j = jc*128 + t;
  float a=0.f, b=0.f;
  for(int k=0;k<D;k++){ float m = mean[k]; a += m*W1b[(size_t)k*D+j]; b += m*Wout[(size_t)k*D+j]; }
  Bpre[lvl*D+j] = a;
  MW[lvl*D+j] = b;
}

// ---- GEMM2 + fused linearized scores: A = Hg@W1a^T never hits memory. ----
// Epilogue: g = w2*(1-tanh(A+b1)^2); partial score p[lev] = sum_cols g*Bpre[lev][col];
// shfl-reduce over l15 (16 cols) -> LDS atomic (2-way: wn=0/1) -> per-block partial
// sblk[by][row][lev] (summed by k_out). NO output matrix write.
__global__ __launch_bounds__(256) void k_gemm2(
    const unsigned short* __restrict__ Xs,
    const unsigned short* __restrict__ Wt,
    const float* __restrict__ Bpre,
    const float* __restrict__ b1,
    const float* __restrict__ w2,
    float* __restrict__ sblk,            // [4][PADMAX][NL]
    const int* __restrict__ poff)
{
  __shared__ __attribute__((aligned(16))) unsigned short Asb[BM*64];
  __shared__ __attribute__((aligned(16))) unsigned short Bsb[BN*64];
  __shared__ float sS[BM][NL];           // 4KB per-block score accumulator
  int row0 = blockIdx.x*BM;
  if(row0 >= poff[NL]) return;
  int n0 = blockIdx.y*BN;
  int tid = threadIdx.x;
  for(int i=tid;i<BM*NL;i+=256) ((float*)sS)[i]=0.f;   // visible after 1st loop barrier
  int l = tid&63, w = tid>>6;
  int wm = w>>1, wn = w&1;
  int l15 = l&15, lhi = l>>4;
  int lo = (l>>3)*D + (l&7)*8;
  const unsigned short* Abase = Xs + (size_t)row0*D + lo;
  const unsigned short* Bbase = Wt + (size_t)n0*D + lo;
  f32x4 acc[4][4];
  #pragma unroll
  for(int i=0;i<4;i++)
    #pragma unroll
    for(int j=0;j<4;j++) acc[i][j] = (f32x4){0.f,0.f,0.f,0.f};

  for(int kt=0;kt<D/64;kt++){
    int k0 = kt*64;
    #pragma unroll
    for(int i=0;i<4;i++)
      GLDS16(Abase + (size_t)((w*4+i)*8)*D + k0, Asb + (w*4+i)*512);
    #pragma unroll
    for(int i=0;i<4;i++)
      GLDS16(Bbase + (size_t)((w*4+i)*8)*D + k0, Bsb + (w*4+i)*512);
    __syncthreads();
    #pragma unroll
    for(int kk=0;kk<2;kk++){
      bf16x8 af[4], bg[4];
      #pragma unroll
      for(int fm=0;fm<4;fm++)
        af[fm] = __builtin_bit_cast(bf16x8, *(const short8*)(Asb + (wm*64+fm*16+l15)*64 + kk*32 + lhi*8));
      #pragma unroll
      for(int fn=0;fn<4;fn++)
        bg[fn] = __builtin_bit_cast(bf16x8, *(const short8*)(Bsb + (wn*64+fn*16+l15)*64 + kk*32 + lhi*8));
      #pragma unroll
      for(int fm=0;fm<4;fm++)
        #pragma unroll
        for(int fn=0;fn<4;fn++)
          acc[fm][fn] = __builtin_amdgcn_mfma_f32_16x16x32_bf16(af[fm], bg[fn], acc[fm][fn], 0,0,0);
    }
    __syncthreads();
  }
  // fused score epilogue
  float b1c[4], w2c[4], Bp[4][NL];
  #pragma unroll
  for(int fn=0;fn<4;fn++){
    int col = n0 + wn*64 + fn*16 + l15;
    b1c[fn] = b1[col]; w2c[fn] = w2[col];
    #pragma unroll
    for(int lev=0;lev<NL;lev++) Bp[fn][lev] = Bpre[lev*D + col];
  }
  #pragma unroll
  for(int fm=0;fm<4;fm++){
    #pragma unroll
    for(int j=0;j<4;j++){
      float p[NL];
      #pragma unroll
      for(int lev=0;lev<NL;lev++) p[lev]=0.f;
      #pragma unroll
      for(int fn=0;fn<4;fn++){
        float u = acc[fm][fn][j] + b1c[fn];
        float t = tanh_fast(u);
        float g = w2c[fn]*(1.f - t*t);
        #pragma unroll
        for(int lev=0;lev<NL;lev++) p[lev] += g*Bp[fn][lev];
      }
      #pragma unroll
      for(int lev=0;lev<NL;lev++){
        float s = p[lev];
        s += __shfl_xor(s,1); s += __shfl_xor(s,2);
        s += __shfl_xor(s,4); s += __shfl_xor(s,8);
        p[lev] = s;
      }
      if(l15==0){
        int lr = wm*64 + fm*16 + lhi*4 + j;
        #pragma unroll
        for(int lev=0;lev<NL;lev++) atomicAdd(&sS[lr][lev], p[lev]);
      }
    }
  }
  __syncthreads();
  if(tid < BM){
    float* dst = sblk + ((size_t)blockIdx.y*PADMAX + row0 + tid)*NL;
    *(f32x4*)dst     = *(f32x4*)&sS[tid][0];
    *(f32x4*)(dst+4) = *(f32x4*)&sS[tid][4];
  }
}

// ---- finisher: sum partial scores -> masked softmax -> o = wts@MW + bout -> LN -> ReLU ----
// No Ag read. MW/bout/gamma/beta hoisted to registers (constant per lane). Write-BW-bound.
__global__ __launch_bounds__(256) void k_out(
    const float* __restrict__ sblk, const int* __restrict__ perm,
    const int* __restrict__ poff, const int* __restrict__ counts,
    const float* __restrict__ MW, const float* __restrict__ bout,
    const float* __restrict__ gamma, const float* __restrict__ beta,
    float* __restrict__ out)
{
  int tid = threadIdx.x, l = tid&63, wv = tid>>6;
  int l8 = l*8;
  int pf[NL+1];
  #pragma unroll
  for(int i=0;i<=NL;i++) pf[i]=poff[i];
  int cl[NL];
  #pragma unroll
  for(int i=0;i<NL;i++) cl[i]=counts[i];
  float mw0[NL][4], mw1[NL][4];
  #pragma unroll
  for(int lev=0;lev<NL;lev++){
    f32x4 a = *(const f32x4*)(MW + lev*D + l8);
    f32x4 b = *(const f32x4*)(MW + lev*D + l8 + 4);
    #pragma unroll
    for(int e=0;e<4;e++){ mw0[lev][e]=a[e]; mw1[lev][e]=b[e]; }
  }
  f32x4 bo0 = *(const f32x4*)(bout + l8),  bo1 = *(const f32x4*)(bout + l8 + 4);
  f32x4 ga0 = *(const f32x4*)(gamma + l8), ga1 = *(const f32x4*)(gamma + l8 + 4);
  f32x4 be0 = *(const f32x4*)(beta + l8),  be1 = *(const f32x4*)(beta + l8 + 4);
  for(int r = blockIdx.x*4 + wv; r < pf[NL]; r += gridDim.x*4){
    int lvl=0;
    #pragma unroll
    for(int i=1;i<NL;i++) lvl += (r>=pf[i]);
    if(r - pf[lvl] >= cl[lvl]) continue;     // padding row (wave-uniform)
    int orig = perm[r];
    float sc[NL];
    #pragma unroll
    for(int lev=0;lev<NL;lev++) sc[lev]=0.f;
    #pragma unroll
    for(int nb=0;nb<4;nb++){
      const float* sp = sblk + ((size_t)nb*PADMAX + r)*NL;
      f32x4 s0 = *(const f32x4*)sp;
      f32x4 s1 = *(const f32x4*)(sp+4);
      #pragma unroll
      for(int e=0;e<4;e++){ sc[e]+=s0[e]; sc[4+e]+=s1[e]; }
    }
    float mx = -1e30f;
    #pragma unroll
    for(int lev=0;lev<NL;lev++) if(cl[lev]>0) mx = fmaxf(mx, sc[lev]);
    float den=0.f, wts[NL];
    #pragma unroll
    for(int lev=0;lev<NL;lev++){ float e=(cl[lev]>0)?__expf(sc[lev]-mx):0.f; wts[lev]=e; den+=e; }
    float iden = 1.f/den;
    #pragma unroll
    for(int lev=0;lev<NL;lev++) wts[lev]*=iden;
    f32x4 o0, o1;
    #pragma unroll
    for(int e=0;e<4;e++){ o0[e]=bo0[e]; o1[e]=bo1[e]; }
    #pragma unroll
    for(int lev=0;lev<NL;lev++){
      float wl = wts[lev];
      #pragma unroll
      for(int e=0;e<4;e++){ o0[e] += wl*mw0[lev][e]; o1[e] += wl*mw1[lev][e]; }
    }
    float s1 = o0[0]+o0[1]+o0[2]+o0[3]+o1[0]+o1[1]+o1[2]+o1[3];
    #pragma unroll
    for(int off=1; off<64; off<<=1) s1 += __shfl_xor(s1,off);
    float mu = s1 * (1.f/512.f);
    float s2=0.f;
    #pragma unroll
    for(int e=0;e<4;e++){ float d0=o0[e]-mu, d1=o1[e]-mu; s2 += d0*d0 + d1*d1; }
    #pragma unroll
    for(int off=1; off<64; off<<=1) s2 += __shfl_xor(s2,off);
    float rs = rsqrtf(s2*(1.f/512.f) + 1e-5f);
    f32x4 y0, y1;
    #pragma unroll
    for(int e=0;e<4;e++){
      y0[e] = fmaxf((o0[e]-mu)*rs*ga0[e] + be0[e], 0.f);
      y1[e] = fmaxf((o1[e]-mu)*rs*ga1[e] + be1[e], 0.f);
    }
    float* op = out + (size_t)orig*D + l8;
    *(f32x4*)op = y0;
    *(f32x4*)(op+4) = y1;
  }
}

extern "C" void kernel_launch(void* const* d_in, const int* in_sizes, int n_in,
                              void* d_out, int out_size, void* d_ws, size_t ws_size,
                              hipStream_t stream) {
  (void)in_sizes; (void)n_in; (void)out_size; (void)ws_size;
  const float* X    = (const float*)d_in[0];
  const int*   lv   = (const int*)  d_in[1];
  const float* Wp   = (const float*)d_in[2];
  const float* bp   = (const float*)d_in[3];
  const float* W1a  = (const float*)d_in[4];
  const float* W1b  = (const float*)d_in[5];
  const float* b1   = (const float*)d_in[6];
  const float* w2   = (const float*)d_in[7];
  const float* b2   = (const float*)d_in[8];
  const float* Wout = (const float*)d_in[9];
  const float* bout = (const float*)d_in[10];
  const float* gmma = (const float*)d_in[11];
  const float* beta = (const float*)d_in[12];
  (void)b2;
  float* out = (float*)d_out;

  char* ws = (char*)d_ws;
  int*   counts  = (int*)(ws+0);        // 8
  int*   cursors = (int*)(ws+64);       // 8
  int*   poff    = (int*)(ws+128);      // 9
  float* sums    = (float*)(ws+256);    // 8*512
  float* Bpre    = (float*)(ws+16640);  // 8*512
  float* MW      = (float*)(ws+33024);  // 8*512
  int*   perm    = (int*)(ws+49664);    // 33792
  unsigned short* WtP  = (unsigned short*)(ws+186368);          // 8*512*512 bf16
  unsigned short* Wt1a = WtP + (size_t)NL*D*D;                  // 512*512 bf16
  unsigned short* Xg   = (unsigned short*)(ws+4905472);         // 33792*512 bf16
  unsigned short* Hg   = (unsigned short*)(ws+39508480);        // 33792*512 bf16
  float* sblk = (float*)(ws+4905472);   // [4][PADMAX][8] partial scores; Xg dead after GEMM1

  k_zero   <<<dim3(9),   dim3(512), 0, stream>>>((float*)ws);
  k_hist   <<<dim3(64),  dim3(256), 0, stream>>>(lv, counts);
  k_offsets<<<dim3(1),   dim3(64),  0, stream>>>(counts, poff, cursors);
  k_scatter<<<dim3(128), dim3(256), 0, stream>>>(lv, cursors, perm);
  k_trans  <<<dim3(8,8,9), dim3(256), 0, stream>>>(Wp, W1a, WtP, Wt1a);
  k_gather <<<dim3(2048), dim3(256), 0, stream>>>(X, perm, poff, counts, Xg);
  k_gemm   <<<dim3(MT_MAX,4), dim3(256), 0, stream>>>(Xg, WtP, bp, Hg, sums, poff, counts);
  k_small  <<<dim3(8,4), dim3(128), 0, stream>>>(sums, counts, W1b, Wout, Bpre, MW);
  k_gemm2  <<<dim3(MT_MAX,4), dim3(256), 0, stream>>>(Hg, Wt1a, Bpre, b1, w2, sblk, poff);
  k_out    <<<dim3(2048), dim3(256), 0, stream>>>(sblk, perm, poff, counts, MW, bout,
                                                  gmma, beta, out);
}